// Round 5
// baseline (140.257 us; speedup 1.0000x reference)
//
#include <hip/hip_runtime.h>
#include <hip/hip_bf16.h>
#include <stdint.h>

typedef __attribute__((ext_vector_type(8))) short short8;
typedef __attribute__((ext_vector_type(4))) float float4_t;

#define DDIM 128
#define SORTN 256
#define LROW 136         // LDS row pitch in shorts (272 B) — breaks 16-way bank aliasing

__device__ inline unsigned short f32_to_bf16_rne(float f) {
    uint32_t u = __float_as_uint(f);
    return (unsigned short)((u + 0x7FFFu + ((u >> 16) & 1u)) >> 16);
}
__device__ inline float bf16_to_f32(unsigned short h) {
    return __uint_as_float(((uint32_t)h) << 16);
}
__device__ inline int ks_of(const int* seq_lens, int n_seq, int t) {
    int off = 0, r = 0;
    for (int i = 0; i < n_seq; ++i) {
        int nx = off + seq_lens[i];
        if (t < nx) { r = off; break; }
        off = nx;
    }
    return r;
}

// ---- pass 1: rotate all q rows (T*H) and k rows (T); one wave per row ----
__global__ __launch_bounds__(256) void rotate_all_kernel(
        const unsigned short* __restrict__ q, const unsigned short* __restrict__ k,
        unsigned short* __restrict__ qr, unsigned short* __restrict__ kr,
        int TH, int T) {
    int row = blockIdx.x * 4 + (threadIdx.x >> 6);
    if (row >= TH + T) return;
    int lane = threadIdx.x & 63;
    const unsigned short* src = (row < TH) ? (q + (size_t)row * DDIM)
                                           : (k + (size_t)(row - TH) * DDIM);
    unsigned short* dst = (row < TH) ? (qr + (size_t)row * DDIM)
                                     : (kr + (size_t)(row - TH) * DDIM);
    ushort2 in = *(const ushort2*)(src + 2 * lane);
    float x0 = bf16_to_f32(in.x), x1 = bf16_to_f32(in.y);
    { float a = x0 + x1, b = x0 - x1; x0 = a; x1 = b; }
    #pragma unroll
    for (int m = 1; m <= 32; m <<= 1) {
        float y0 = __shfl_xor(x0, m, 64);
        float y1 = __shfl_xor(x1, m, 64);
        bool hi = (lane & m) != 0;
        x0 = hi ? (y0 - x0) : (x0 + y0);
        x1 = hi ? (y1 - x1) : (x1 + y1);
    }
    const float sc = 0.08838834764831845f;
    ushort2 o; o.x = f32_to_bf16_rne(x0 * sc); o.y = f32_to_bf16_rne(x1 * sc);
    *(ushort2*)(dst + 2 * lane) = o;
}

// ---- pass 2: score GEMM. block = 8 tokens x 16 heads (M=128) x 128 kv ----
__global__ __launch_bounds__(256, 2) void score_kernel(
        const unsigned short* __restrict__ qr,  // [T*H,128]
        const unsigned short* __restrict__ kr,  // [T,128]
        const float* __restrict__ w,            // [T,H]
        const int* __restrict__ seq_lens, int n_seq,
        float* __restrict__ scores,             // [T, P]
        int T, int H, int P) {
    __shared__ __align__(16) unsigned short aL[128 * LROW];
    __shared__ __align__(16) unsigned short bL[128 * LROW];

    const int ttile = blockIdx.y;
    const int tt0   = ttile * 8;
    const int bks   = ks_of(seq_lens, n_seq, tt0);
    const int kv0   = bks + (int)blockIdx.x * 128;
    if (kv0 >= tt0 + 8 || kv0 >= T) return;     // no token in tile needs these kv

    const int tid = threadIdx.x, wv = tid >> 6, lane = tid & 63;
    const int col = lane & 15, kgrp = lane >> 4;
    const int srow = tid >> 4, sseg = tid & 15;

    // stage A (qr rows tt0*H .. +127) and B (kr rows kv0..kv0+127), coalesced
    const unsigned short* Abase = qr + (size_t)tt0 * H * DDIM;
    #pragma unroll
    for (int it = 0; it < 8; ++it) {
        int r = srow + 16 * it;
        *(short8*)&aL[r * LROW + sseg * 8] =
            *(const short8*)(Abase + (size_t)r * DDIM + sseg * 8);
    }
    #pragma unroll
    for (int it = 0; it < 8; ++it) {
        int r = srow + 16 * it;
        int gs = kv0 + r; if (gs > T - 1) gs = T - 1;
        *(short8*)&bL[r * LROW + sseg * 8] =
            *(const short8*)(kr + (size_t)gs * DDIM + sseg * 8);
    }
    __syncthreads();

    // A-frags: wave owns m rows [wv*32, wv*32+32) = tokens tt0+wv*2, +1 (16 heads each)
    short8 af[2][4];
    #pragma unroll
    for (int mt = 0; mt < 2; ++mt)
        #pragma unroll
        for (int kk = 0; kk < 4; ++kk)
            af[mt][kk] = *(const short8*)&aL[(wv * 32 + mt * 16 + col) * LROW + kgrp * 8 + kk * 32];

    float4_t acc[2][8];
    #pragma unroll
    for (int mt = 0; mt < 2; ++mt)
        #pragma unroll
        for (int nt = 0; nt < 8; ++nt)
            acc[mt][nt] = (float4_t){0.f, 0.f, 0.f, 0.f};

    #pragma unroll
    for (int nt = 0; nt < 8; ++nt) {
        #pragma unroll
        for (int kk = 0; kk < 4; ++kk) {
            short8 bf = *(const short8*)&bL[(nt * 16 + col) * LROW + kgrp * 8 + kk * 32];
            acc[0][nt] = __builtin_amdgcn_mfma_f32_16x16x32_bf16(af[0][kk], bf, acc[0][nt], 0, 0, 0);
            acc[1][nt] = __builtin_amdgcn_mfma_f32_16x16x32_bf16(af[1][kk], bf, acc[1][nt], 0, 0, 0);
        }
    }

    // epilogue: relu, weight, reduce 16 heads -> score(t, s); write valid entries
    #pragma unroll
    for (int mt = 0; mt < 2; ++mt) {
        const int t = tt0 + wv * 2 + mt;
        const int ks_t = ks_of(seq_lens, n_seq, t);
        float w4[4];
        #pragma unroll
        for (int r = 0; r < 4; ++r) w4[r] = w[(size_t)t * H + kgrp * 4 + r];
        #pragma unroll
        for (int nt = 0; nt < 8; ++nt) {
            float p = 0.f;
            #pragma unroll
            for (int r = 0; r < 4; ++r) {
                float v = acc[mt][nt][r];
                v = v > 0.f ? v : 0.f;
                p += w4[r] * v;
            }
            p += __shfl_xor(p, 16, 64);
            p += __shfl_xor(p, 32, 64);
            int s = kv0 + nt * 16 + col;
            if (lane < 16 && s >= ks_t && s <= t)
                scores[(size_t)t * P + (s - ks_t)] = p;
        }
    }
}

// ---- pass 3: per-token exact top-K selection (one wave per token) ----
template <int NCHT>
__device__ __forceinline__ void do_select(
        const float* __restrict__ row, int n, int ks, int ke, int T, int K,
        int lane, unsigned long long* __restrict__ candw,
        float* __restrict__ ov, float* __restrict__ oi, int t) {
    const int nch = (n + 63) >> 6;
    uint32_t ukey[NCHT];
    #pragma unroll
    for (int c = 0; c < NCHT; ++c) {
        if (c < nch) {
            int i = c * 64 + lane;
            ukey[c] = (i < n) ? __float_as_uint(row[i]) : 0u;
        } else ukey[c] = 0u;
    }

    const int Keff = (n < K) ? n : K;
    uint32_t ustar = 0;
    int ttake = K;
    if (n > K) {
        uint32_t lo = 0, hi = 0x80000000u;
        for (int it = 0; it < 31; ++it) {
            uint32_t mid = (lo + hi) >> 1;
            int cnt = 0;
            #pragma unroll
            for (int c = 0; c < NCHT; ++c)
                if (c < nch) cnt += (int)__popcll(__ballot(ukey[c] >= mid));
            if (cnt >= K) lo = mid; else hi = mid;
        }
        ustar = lo;
        int cnt_gt = 0;
        #pragma unroll
        for (int c = 0; c < NCHT; ++c)
            if (c < nch) cnt_gt += (int)__popcll(__ballot(ukey[c] > ustar));
        ttake = K - cnt_gt;
    }

    {
        const unsigned long long ltm = (1ull << lane) - 1ull;
        int base = 0, tieBase = 0;
        const bool selAll = (n <= K);
        #pragma unroll
        for (int c = 0; c < NCHT; ++c) {
            if (c < nch) {
                int i = c * 64 + lane;
                bool inb = (i < n);
                uint32_t u = ukey[c];
                bool isGt  = inb && (selAll || u > ustar);
                bool isTie = inb && !selAll && (u == ustar);
                unsigned long long mt = __ballot(isTie);
                int tr = tieBase + (int)__popcll(mt & ltm);
                bool take = isGt || (isTie && tr < ttake);
                unsigned long long m = __ballot(take);
                if (take) {
                    int pos = base + (int)__popcll(m & ltm);
                    int s = ks + i;
                    candw[pos] = ((((unsigned long long)u << 11) |
                                   (unsigned long long)(T - 1 - s)) + 1ull);
                }
                base    += (int)__popcll(m);
                tieBase += (int)__popcll(mt);
            }
        }
        for (int i = Keff + lane; i < SORTN; i += 64) candw[i] = 0ull;
    }

    unsigned long long kreg[4];
    #pragma unroll
    for (int r = 0; r < 4; ++r) kreg[r] = candw[4 * lane + r];

    #define CX(a, b, dsc) { unsigned long long _mx = (a) > (b) ? (a) : (b); \
                            unsigned long long _mn = (a) > (b) ? (b) : (a); \
                            (a) = (dsc) ? _mx : _mn; (b) = (dsc) ? _mn : _mx; }
    #pragma unroll
    for (int size = 2; size <= SORTN; size <<= 1) {
        #pragma unroll
        for (int stride = SORTN >> 1; stride >= 4; stride >>= 1) {
            if (stride > (size >> 1)) continue;
            int lmask = stride >> 2;
            #pragma unroll
            for (int r = 0; r < 4; ++r) {
                int e = 4 * lane + r;
                unsigned long long other = __shfl_xor(kreg[r], lmask, 64);
                bool desc = ((e & size) == 0);
                bool iAmLow = ((e & stride) == 0);
                bool keepMax = (iAmLow == desc);
                kreg[r] = keepMax ? (kreg[r] > other ? kreg[r] : other)
                                  : (kreg[r] < other ? kreg[r] : other);
            }
        }
        if (size >= 4) {
            bool d = (((4 * lane) & size) == 0);
            CX(kreg[0], kreg[2], d);
            CX(kreg[1], kreg[3], d);
            CX(kreg[0], kreg[1], d);
            CX(kreg[2], kreg[3], d);
        } else {
            CX(kreg[0], kreg[1], true);
            CX(kreg[2], kreg[3], false);
        }
    }
    #undef CX

    if (4 * lane < K) {
        float4_t v4, i4;
        #pragma unroll
        for (int r = 0; r < 4; ++r) {
            int e = 4 * lane + r;
            unsigned long long key = kreg[r];
            float v; int idx;
            if (key != 0ull) {
                unsigned long long km1 = key - 1ull;
                v = __uint_as_float((uint32_t)(km1 >> 11));
                idx = T - 1 - (int)(km1 & 0x7FFull);
            } else {
                int pidx = e - Keff;
                idx = (pidx < ks) ? pidx : (ke + (pidx - ks));
                v = -1e30f;
            }
            v4[r] = v; i4[r] = (float)idx;
        }
        *(float4_t*)(ov + (size_t)t * K + 4 * lane) = v4;
        *(float4_t*)(oi + (size_t)t * K + 4 * lane) = i4;
    }
}

__global__ __launch_bounds__(256) void select_kernel(
        const float* __restrict__ scores, const int* __restrict__ seq_lens, int n_seq,
        float* __restrict__ out_vals, float* __restrict__ out_idx,
        int T, int P, int K) {
    __shared__ unsigned long long cand[4][SORTN];
    const int wv = threadIdx.x >> 6, lane = threadIdx.x & 63;
    const int t = T - 1 - ((int)blockIdx.x * 4 + wv);
    if (t < 0) return;
    const int ks = ks_of(seq_lens, n_seq, t);
    const int ke = t + 1;
    const int n  = ke - ks;
    const float* row = scores + (size_t)t * P;
    if (n <= 1024)
        do_select<16>(row, n, ks, ke, T, K, lane, cand[wv], out_vals, out_idx, t);
    else
        do_select<32>(row, n, ks, ke, T, K, lane, cand[wv], out_vals, out_idx, t);
}

extern "C" void kernel_launch(void* const* d_in, const int* in_sizes, int n_in,
                              void* d_out, int out_size, void* d_ws, size_t ws_size,
                              hipStream_t stream) {
    const unsigned short* q = (const unsigned short*)d_in[0];
    const unsigned short* k = (const unsigned short*)d_in[1];
    const float* w          = (const float*)d_in[2];
    const int* seq_lens     = (const int*)d_in[3];
    const int n_seq = in_sizes[3];
    const int T = in_sizes[1] / DDIM;
    const int H = in_sizes[2] / T;
    const int K = out_size / (2 * T);
    const int P = T + 64;                        // score-row pitch

    // ws layout: scores f32[T*P] | qr bf16[T*H*128] | kr bf16[T*128]  (~26 MB)
    float* scores = (float*)d_ws;
    unsigned short* qr = (unsigned short*)(scores + (size_t)T * P);
    unsigned short* kr = qr + (size_t)T * H * DDIM;

    float* out_vals = (float*)d_out;
    float* out_idx  = out_vals + (size_t)T * K;

    const int TH = T * H;
    rotate_all_kernel<<<dim3((TH + T + 3) / 4), dim3(256), 0, stream>>>(q, k, qr, kr, TH, T);
    dim3 sg((T + 127) / 128, (T + 7) / 8);
    score_kernel<<<sg, dim3(256), 0, stream>>>(qr, kr, w, seq_lens, n_seq, scores, T, H, P);
    select_kernel<<<dim3((T + 3) / 4), dim3(256), 0, stream>>>(
        scores, seq_lens, n_seq, out_vals, out_idx, T, P, K);
}

// Round 6
// 137.174 us; speedup vs baseline: 1.0225x; 1.0225x over previous
//
#include <hip/hip_runtime.h>
#include <hip/hip_bf16.h>
#include <stdint.h>

typedef __attribute__((ext_vector_type(8))) short short8;
typedef __attribute__((ext_vector_type(4))) float float4_t;

#define DDIM 128
#define SORTN 256
#define LROW 136         // LDS row pitch in shorts (272 B) — breaks 16-way bank aliasing

__device__ inline unsigned short f32_to_bf16_rne(float f) {
    uint32_t u = __float_as_uint(f);
    return (unsigned short)((u + 0x7FFFu + ((u >> 16) & 1u)) >> 16);
}
__device__ inline float bf16_to_f32(unsigned short h) {
    return __uint_as_float(((uint32_t)h) << 16);
}
__device__ inline int ks_of(const int* seq_lens, int n_seq, int t) {
    int off = 0, r = 0;
    for (int i = 0; i < n_seq; ++i) {
        int nx = off + seq_lens[i];
        if (t < nx) { r = off; break; }
        off = nx;
    }
    return r;
}

// ---- pass 1: rotate all q rows (T*H) and k rows (T); 4 rows per wave ----
// lane layout: row = blk*16 + (tid>>4), elements [8*(tid&15) .. +8)
__global__ __launch_bounds__(256) void rotate_all_kernel(
        const unsigned short* __restrict__ q, const unsigned short* __restrict__ k,
        unsigned short* __restrict__ qr, unsigned short* __restrict__ kr,
        int TH, int T) {
    int row = blockIdx.x * 16 + (threadIdx.x >> 4);
    if (row >= TH + T) return;
    int l16 = threadIdx.x & 15;
    const unsigned short* src = (row < TH) ? (q + (size_t)row * DDIM)
                                           : (k + (size_t)(row - TH) * DDIM);
    unsigned short* dst = (row < TH) ? (qr + (size_t)row * DDIM)
                                     : (kr + (size_t)(row - TH) * DDIM);
    short8 in = *(const short8*)(src + 8 * l16);
    float f[8];
    #pragma unroll
    for (int j = 0; j < 8; ++j) f[j] = bf16_to_f32((unsigned short)in[j]);
    // element-index bits 1,2,4 in-register
    #pragma unroll
    for (int b = 1; b <= 4; b <<= 1)
        #pragma unroll
        for (int j = 0; j < 8; ++j)
            if (!(j & b)) { float a = f[j], c = f[j | b]; f[j] = a + c; f[j | b] = a - c; }
    // element-index bits 8,16,32,64 via shfl_xor 1,2,4,8 (within 16-lane row group)
    #pragma unroll
    for (int m = 1; m <= 8; m <<= 1) {
        bool hi = (l16 & m) != 0;
        #pragma unroll
        for (int j = 0; j < 8; ++j) {
            float o = __shfl_xor(f[j], m, 64);
            f[j] = hi ? (o - f[j]) : (f[j] + o);
        }
    }
    const float sc = 0.08838834764831845f;
    short8 out;
    #pragma unroll
    for (int j = 0; j < 8; ++j) out[j] = (short)f32_to_bf16_rne(f[j] * sc);
    *(short8*)(dst + 8 * l16) = out;
}

// ---- pass 2: score GEMM. block = 8 tokens x 16 heads (M=128) x 128 kv ----
__global__ __launch_bounds__(256, 2) void score_kernel(
        const unsigned short* __restrict__ qr,  // [T*H,128]
        const unsigned short* __restrict__ kr,  // [T,128]
        const float* __restrict__ w,            // [T,H]
        const int* __restrict__ seq_lens, int n_seq,
        float* __restrict__ scores,             // [T, P]
        int T, int H, int P) {
    __shared__ __align__(16) unsigned short aL[128 * LROW];
    __shared__ __align__(16) unsigned short bL[128 * LROW];

    const int ttile = blockIdx.y;
    const int tt0   = ttile * 8;
    const int bks   = ks_of(seq_lens, n_seq, tt0);
    const int kv0   = bks + (int)blockIdx.x * 128;
    if (kv0 >= tt0 + 8 || kv0 >= T) return;

    const int tid = threadIdx.x, wv = tid >> 6, lane = tid & 63;
    const int col = lane & 15, kgrp = lane >> 4;
    const int srow = tid >> 4, sseg = tid & 15;

    const unsigned short* Abase = qr + (size_t)tt0 * H * DDIM;
    #pragma unroll
    for (int it = 0; it < 8; ++it) {
        int r = srow + 16 * it;
        *(short8*)&aL[r * LROW + sseg * 8] =
            *(const short8*)(Abase + (size_t)r * DDIM + sseg * 8);
    }
    #pragma unroll
    for (int it = 0; it < 8; ++it) {
        int r = srow + 16 * it;
        int gs = kv0 + r; if (gs > T - 1) gs = T - 1;
        *(short8*)&bL[r * LROW + sseg * 8] =
            *(const short8*)(kr + (size_t)gs * DDIM + sseg * 8);
    }
    __syncthreads();

    short8 af[2][4];
    #pragma unroll
    for (int mt = 0; mt < 2; ++mt)
        #pragma unroll
        for (int kk = 0; kk < 4; ++kk)
            af[mt][kk] = *(const short8*)&aL[(wv * 32 + mt * 16 + col) * LROW + kgrp * 8 + kk * 32];

    float4_t acc[2][8];
    #pragma unroll
    for (int mt = 0; mt < 2; ++mt)
        #pragma unroll
        for (int nt = 0; nt < 8; ++nt)
            acc[mt][nt] = (float4_t){0.f, 0.f, 0.f, 0.f};

    #pragma unroll
    for (int nt = 0; nt < 8; ++nt) {
        #pragma unroll
        for (int kk = 0; kk < 4; ++kk) {
            short8 bf = *(const short8*)&bL[(nt * 16 + col) * LROW + kgrp * 8 + kk * 32];
            acc[0][nt] = __builtin_amdgcn_mfma_f32_16x16x32_bf16(af[0][kk], bf, acc[0][nt], 0, 0, 0);
            acc[1][nt] = __builtin_amdgcn_mfma_f32_16x16x32_bf16(af[1][kk], bf, acc[1][nt], 0, 0, 0);
        }
    }

    #pragma unroll
    for (int mt = 0; mt < 2; ++mt) {
        const int t = tt0 + wv * 2 + mt;
        const int ks_t = ks_of(seq_lens, n_seq, t);
        float w4[4];
        #pragma unroll
        for (int r = 0; r < 4; ++r) w4[r] = w[(size_t)t * H + kgrp * 4 + r];
        #pragma unroll
        for (int nt = 0; nt < 8; ++nt) {
            float p = 0.f;
            #pragma unroll
            for (int r = 0; r < 4; ++r) {
                float v = acc[mt][nt][r];
                v = v > 0.f ? v : 0.f;
                p += w4[r] * v;
            }
            p += __shfl_xor(p, 16, 64);
            p += __shfl_xor(p, 32, 64);
            int s = kv0 + nt * 16 + col;
            if (lane < 16 && s >= ks_t && s <= t)
                scores[(size_t)t * P + (s - ks_t)] = p;
        }
    }
}

// ---- pass 3: per-token exact top-K selection (one wave per token) ----
// Binary search counting is pure VALU (per-lane predicate adds + shfl reduce);
// no ballot/SALU round-trips in the 31-iteration serial chain.
template <int NCHT>
__device__ __forceinline__ void do_select(
        const float* __restrict__ row, int n, int ks, int ke, int T, int K,
        int lane, unsigned long long* __restrict__ candw,
        float* __restrict__ ov, float* __restrict__ oi, int t) {
    const int nch = (n + 63) >> 6;
    uint32_t ukey[NCHT];
    #pragma unroll
    for (int c = 0; c < NCHT; ++c) {
        if (c < nch) {
            int i = c * 64 + lane;
            ukey[c] = (i < n) ? __float_as_uint(row[i]) : 0u;
        } else ukey[c] = 0u;
    }

    const int Keff = (n < K) ? n : K;
    uint32_t ustar = 0;
    int ttake = K;
    if (n > K) {
        uint32_t lo = 0, hi = 0x80000000u;
        for (int it = 0; it < 31; ++it) {
            uint32_t mid = (lo + hi) >> 1;     // >= 1 while hi-lo >= 2
            int lc = 0;
            #pragma unroll
            for (int c = 0; c < NCHT; ++c)
                if (c < nch) lc += (ukey[c] >= mid) ? 1 : 0;
            #pragma unroll
            for (int off = 1; off <= 32; off <<= 1)
                lc += __shfl_xor(lc, off, 64);
            if (lc >= K) lo = mid; else hi = mid;
        }
        ustar = lo;
        int lg = 0;
        #pragma unroll
        for (int c = 0; c < NCHT; ++c)
            if (c < nch) lg += (ukey[c] > ustar) ? 1 : 0;
        #pragma unroll
        for (int off = 1; off <= 32; off <<= 1)
            lg += __shfl_xor(lg, off, 64);
        ttake = K - lg;
    }

    {
        const unsigned long long ltm = (1ull << lane) - 1ull;
        int base = 0, tieBase = 0;
        const bool selAll = (n <= K);
        #pragma unroll
        for (int c = 0; c < NCHT; ++c) {
            if (c < nch) {
                int i = c * 64 + lane;
                bool inb = (i < n);
                uint32_t u = ukey[c];
                bool isGt  = inb && (selAll || u > ustar);
                bool isTie = inb && !selAll && (u == ustar);
                unsigned long long mt = __ballot(isTie);
                int tr = tieBase + (int)__popcll(mt & ltm);
                bool take = isGt || (isTie && tr < ttake);
                unsigned long long m = __ballot(take);
                if (take) {
                    int pos = base + (int)__popcll(m & ltm);
                    int s = ks + i;
                    candw[pos] = ((((unsigned long long)u << 11) |
                                   (unsigned long long)(T - 1 - s)) + 1ull);
                }
                base    += (int)__popcll(m);
                tieBase += (int)__popcll(mt);
            }
        }
        for (int i = Keff + lane; i < SORTN; i += 64) candw[i] = 0ull;
    }

    unsigned long long kreg[4];
    #pragma unroll
    for (int r = 0; r < 4; ++r) kreg[r] = candw[4 * lane + r];

    #define CX(a, b, dsc) { unsigned long long _mx = (a) > (b) ? (a) : (b); \
                            unsigned long long _mn = (a) > (b) ? (b) : (a); \
                            (a) = (dsc) ? _mx : _mn; (b) = (dsc) ? _mn : _mx; }
    #pragma unroll
    for (int size = 2; size <= SORTN; size <<= 1) {
        #pragma unroll
        for (int stride = SORTN >> 1; stride >= 4; stride >>= 1) {
            if (stride > (size >> 1)) continue;
            int lmask = stride >> 2;
            #pragma unroll
            for (int r = 0; r < 4; ++r) {
                int e = 4 * lane + r;
                unsigned long long other = __shfl_xor(kreg[r], lmask, 64);
                bool desc = ((e & size) == 0);
                bool iAmLow = ((e & stride) == 0);
                bool keepMax = (iAmLow == desc);
                kreg[r] = keepMax ? (kreg[r] > other ? kreg[r] : other)
                                  : (kreg[r] < other ? kreg[r] : other);
            }
        }
        if (size >= 4) {
            bool d = (((4 * lane) & size) == 0);
            CX(kreg[0], kreg[2], d);
            CX(kreg[1], kreg[3], d);
            CX(kreg[0], kreg[1], d);
            CX(kreg[2], kreg[3], d);
        } else {
            CX(kreg[0], kreg[1], true);
            CX(kreg[2], kreg[3], false);
        }
    }
    #undef CX

    if (4 * lane < K) {
        float4_t v4, i4;
        #pragma unroll
        for (int r = 0; r < 4; ++r) {
            int e = 4 * lane + r;
            unsigned long long key = kreg[r];
            float v; int idx;
            if (key != 0ull) {
                unsigned long long km1 = key - 1ull;
                v = __uint_as_float((uint32_t)(km1 >> 11));
                idx = T - 1 - (int)(km1 & 0x7FFull);
            } else {
                int pidx = e - Keff;
                idx = (pidx < ks) ? pidx : (ke + (pidx - ks));
                v = -1e30f;
            }
            v4[r] = v; i4[r] = (float)idx;
        }
        *(float4_t*)(ov + (size_t)t * K + 4 * lane) = v4;
        *(float4_t*)(oi + (size_t)t * K + 4 * lane) = i4;
    }
}

__global__ __launch_bounds__(256) void select_kernel(
        const float* __restrict__ scores, const int* __restrict__ seq_lens, int n_seq,
        float* __restrict__ out_vals, float* __restrict__ out_idx,
        int T, int P, int K) {
    __shared__ unsigned long long cand[4][SORTN];
    const int wv = threadIdx.x >> 6, lane = threadIdx.x & 63;
    const int t = T - 1 - ((int)blockIdx.x * 4 + wv);
    if (t < 0) return;
    const int ks = ks_of(seq_lens, n_seq, t);
    const int ke = t + 1;
    const int n  = ke - ks;
    const float* row = scores + (size_t)t * P;
    if (n <= 1024)
        do_select<16>(row, n, ks, ke, T, K, lane, cand[wv], out_vals, out_idx, t);
    else
        do_select<32>(row, n, ks, ke, T, K, lane, cand[wv], out_vals, out_idx, t);
}

extern "C" void kernel_launch(void* const* d_in, const int* in_sizes, int n_in,
                              void* d_out, int out_size, void* d_ws, size_t ws_size,
                              hipStream_t stream) {
    const unsigned short* q = (const unsigned short*)d_in[0];
    const unsigned short* k = (const unsigned short*)d_in[1];
    const float* w          = (const float*)d_in[2];
    const int* seq_lens     = (const int*)d_in[3];
    const int n_seq = in_sizes[3];
    const int T = in_sizes[1] / DDIM;
    const int H = in_sizes[2] / T;
    const int K = out_size / (2 * T);
    const int P = T + 64;

    // ws layout: scores f32[T*P] | qr bf16[T*H*128] | kr bf16[T*128]
    float* scores = (float*)d_ws;
    unsigned short* qr = (unsigned short*)(scores + (size_t)T * P);
    unsigned short* kr = qr + (size_t)T * H * DDIM;

    float* out_vals = (float*)d_out;
    float* out_idx  = out_vals + (size_t)T * K;

    const int TH = T * H;
    rotate_all_kernel<<<dim3((TH + T + 15) / 16), dim3(256), 0, stream>>>(q, k, qr, kr, TH, T);
    dim3 sg((T + 127) / 128, (T + 7) / 8);
    score_kernel<<<sg, dim3(256), 0, stream>>>(qr, kr, w, seq_lens, n_seq, scores, T, H, P);
    select_kernel<<<dim3((T + 3) / 4), dim3(256), 0, stream>>>(
        scores, seq_lens, n_seq, out_vals, out_idx, T, P, K);
}